// Round 5
// baseline (475.041 us; speedup 1.0000x reference)
//
#include <hip/hip_runtime.h>

#define NB 4
#define SEQ 2048
#define NH 16
#define HD 64
#define DMODEL 1024

typedef short bf16x8 __attribute__((ext_vector_type(8)));
typedef float f32x16 __attribute__((ext_vector_type(16)));

union FragU {
    bf16x8 v;
    uint2 u2[2];
    unsigned int w[4];
    unsigned short s[8];
};

// Pack two f32 -> packed bf16 pair (lo in low 16 bits).
#if __has_builtin(__builtin_amdgcn_cvt_pk_bf16_f32)
typedef __bf16 v2bf_t __attribute__((ext_vector_type(2)));
__device__ __forceinline__ unsigned int pack_bf16(float lo, float hi) {
    union { v2bf_t h; unsigned int u; } cv;
    cv.h = __builtin_amdgcn_cvt_pk_bf16_f32(lo, hi);
    return cv.u;
}
#else
__device__ __forceinline__ unsigned int pack_bf16(float lo, float hi) {
    unsigned int a = __float_as_uint(lo) + 0x8000u;
    unsigned int b = __float_as_uint(hi) + 0x8000u;
    return __builtin_amdgcn_perm(b, a, 0x07060302);  // {b.hi16, a.hi16}
}
#endif

#define EXP_SCALE 1.44269504f   // 1/ln2, folded into Q and bias table
#define LN2       0.69314718f   // folded into epilogue store

// Block: 512 threads = 8 waves; each wave computes a 32q x 64d output tile.
// Double-buffered LDS K/V tiles, ONE barrier per iteration: global loads for
// tile i+1 are issued before compute of tile i and land in LDS buf (i+1)&1
// after compute — global latency never sits on the critical path.
// X^T = 1.4427*(K*Q^T + bias) via scaled Q + bias-initialized MFMA accumulator
// (C layout: lane=q col); p = x*rcp(1+exp2(-x)); P feeds directly as A-operand
// of P*V (k-slot permutation matched by V fragment addressing); epilogue * ln2.
__global__ __launch_bounds__(512, 4)
void paa_kernel(const float* __restrict__ Vg, const float* __restrict__ Kg,
                const float* __restrict__ Qg, const float* __restrict__ RW,
                float* __restrict__ Og)
{
    __shared__ __align__(16) unsigned short KsLds[2][64 * 68];  // [buf][kc][d], stride 68
    __shared__ __align__(16) unsigned short VtLds[2][64 * 68];  // [buf][d][kc], stride 68
    __shared__ float btab[128];  // 1.4427*bias by distance, clamped at 127

    const int tid  = threadIdx.x;
    const int lane = tid & 63;
    const int wave = tid >> 6;   // 0..7
    const int half = lane >> 5;
    const int l31  = lane & 31;

    const int bid  = blockIdx.x;
    const int bh   = bid & 63;
    const int qt   = bid >> 6;   // 0..7
    const int b    = bh >> 4;
    const int head = bh & 15;

    const int q0w = qt * 256 + wave * 32;   // 32 q rows per wave

    // ---- bias table (pre-scaled by 1/ln2) ----
    if (tid < 128) {
        int rp = tid;
        int bucket;
        if (rp < 16) bucket = rp;
        else {
            int big = 16 + (int)(logf((float)rp * 0.0625f) * 7.6943736f); // 16/ln(8)
            bucket = big < 31 ? big : 31;
        }
        btab[tid] = RW[bucket * NH + head] * EXP_SCALE;
    }

    // ---- preload Q fragments (B operand of S^T), pre-scaled by 1/ln2 ----
    FragU qf[4];
    {
        const float* qrow = Qg + (size_t)(b * SEQ + q0w + l31) * DMODEL + head * HD;
        #pragma unroll
        for (int kf = 0; kf < 4; ++kf) {
            int dd = kf * 16 + half * 8;
            float4 x0 = *(const float4*)(qrow + dd);
            float4 x1 = *(const float4*)(qrow + dd + 4);
            FragU f;
            f.w[0] = pack_bf16(x0.x * EXP_SCALE, x0.y * EXP_SCALE);
            f.w[1] = pack_bf16(x0.z * EXP_SCALE, x0.w * EXP_SCALE);
            f.w[2] = pack_bf16(x1.x * EXP_SCALE, x1.y * EXP_SCALE);
            f.w[3] = pack_bf16(x1.z * EXP_SCALE, x1.w * EXP_SCALE);
            qf[kf] = f;
        }
    }

    f32x16 oacc[2];
    #pragma unroll
    for (int n = 0; n < 2; ++n)
        #pragma unroll
        for (int r = 0; r < 16; ++r) oacc[n][r] = 0.0f;

    // ---- staging roles: threads 0-255 stage K, 256-511 stage V(transposed) ----
    const int st_idx = tid & 255;
    const bool isK   = tid < 256;
    const int srow   = st_idx >> 4;   // K: base row (0..15, +16i) | V: kc4 (0..15)
    const int scol   = st_idx & 15;   // *4 = d-col base
    const float* sbase = (isK ? Kg : Vg) + (size_t)(b * SEQ) * DMODEL + head * HD;

    float4 pre[4];
    // prefetch tile 0
    if (isK) {
        #pragma unroll
        for (int i = 0; i < 4; ++i)
            pre[i] = *(const float4*)(sbase + (size_t)(srow + i * 16) * DMODEL + scol * 4);
    } else {
        #pragma unroll
        for (int r = 0; r < 4; ++r)
            pre[r] = *(const float4*)(sbase + (size_t)(srow * 4 + r) * DMODEL + scol * 4);
    }
    __syncthreads();   // btab ready
    const float bias_d0  = btab[0];    // all d <= 0  -> bucket 0
    const float bias_far = btab[127];  // all d >= 113 -> bucket 31

    // write tile 0 into buf 0
    {
        const float* pf32 = (const float*)pre;
        if (isK) {
            #pragma unroll
            for (int i = 0; i < 4; ++i) {
                uint2 w;
                w.x = pack_bf16(pre[i].x, pre[i].y);
                w.y = pack_bf16(pre[i].z, pre[i].w);
                *(uint2*)&KsLds[0][(srow + i * 16) * 68 + scol * 4] = w;
            }
        } else {
            #pragma unroll
            for (int c = 0; c < 4; ++c) {
                uint2 w;
                w.x = pack_bf16(pf32[0 * 4 + c], pf32[1 * 4 + c]);
                w.y = pack_bf16(pf32[2 * 4 + c], pf32[3 * 4 + c]);
                *(uint2*)&VtLds[0][(scol * 4 + c) * 68 + srow * 4] = w;
            }
        }
    }
    __syncthreads();

    for (int it = 0; it < 32; ++it) {
        const int kcb = it * 64;
        const int cur = it & 1;
        const int nxt = cur ^ 1;

        // ---- issue next tile's global loads (land during compute) ----
        if (it < 31) {
            const float* nb = sbase + (size_t)(kcb + 64) * DMODEL;
            if (isK) {
                #pragma unroll
                for (int i = 0; i < 4; ++i)
                    pre[i] = *(const float4*)(nb + (size_t)(srow + i * 16) * DMODEL + scol * 4);
            } else {
                #pragma unroll
                for (int r = 0; r < 4; ++r)
                    pre[r] = *(const float4*)(nb + (size_t)(srow * 4 + r) * DMODEL + scol * 4);
            }
        }

        // ---- X^T = K * Q^T + bias (bias in accumulator init); silu -> P ----
        FragU pf[4];
        #pragma unroll
        for (int t = 0; t < 2; ++t) {
            const int kcmin = kcb + t * 32;
            FragU ka[4];
            #pragma unroll
            for (int kf = 0; kf < 4; ++kf) {
                int off = (t * 32 + l31) * 68 + kf * 16 + half * 8;
                ka[kf].u2[0] = *(const uint2*)&KsLds[cur][off];
                ka[kf].u2[1] = *(const uint2*)&KsLds[cur][off + 4];
            }
            f32x16 st;
            if (q0w + 31 - kcmin <= 0) {               // whole tile d<=0
                #pragma unroll
                for (int r = 0; r < 16; ++r) st[r] = bias_d0;
            } else if (q0w - (kcmin + 31) >= 113) {    // whole tile bucket 31
                #pragma unroll
                for (int r = 0; r < 16; ++r) st[r] = bias_far;
            } else {                                   // mixed band (~9% of tiles)
                const int dql = q0w + l31 - kcmin - 4 * half;
                #pragma unroll
                for (int r = 0; r < 16; ++r) {
                    int dv = dql - ((r & 3) + 8 * (r >> 2));
                    dv = dv < 0 ? 0 : (dv > 127 ? 127 : dv);
                    st[r] = btab[dv];
                }
            }
            #pragma unroll
            for (int kf = 0; kf < 4; ++kf)
                st = __builtin_amdgcn_mfma_f32_32x32x16_bf16(ka[kf].v, qf[kf].v, st, 0, 0, 0);

            // p = x * rcp(1 + exp2(-x))  == 1.4427 * silu(x*ln2)
            float vals[16];
            #pragma unroll
            for (int r = 0; r < 16; ++r) {
                float x = st[r];
                float e = __builtin_amdgcn_exp2f(-x);
                vals[r] = x * __builtin_amdgcn_rcpf(1.0f + e);
            }
            #pragma unroll
            for (int j = 0; j < 4; ++j)
                pf[t * 2].w[j]     = pack_bf16(vals[2 * j], vals[2 * j + 1]);
            #pragma unroll
            for (int j = 0; j < 4; ++j)
                pf[t * 2 + 1].w[j] = pack_bf16(vals[8 + 2 * j], vals[9 + 2 * j]);
        }

        // ---- O += P * V : V B-fragments address-matched to P's k-slot permutation ----
        #pragma unroll
        for (int f = 0; f < 4; ++f) {
            #pragma unroll
            for (int n = 0; n < 2; ++n) {
                FragU vf;
                int off = (n * 32 + l31) * 68 + f * 16 + half * 4;
                vf.u2[0] = *(const uint2*)&VtLds[cur][off];      // kc offsets 4h..4h+3
                vf.u2[1] = *(const uint2*)&VtLds[cur][off + 8];  // kc offsets 4h+8..4h+11
                oacc[n] = __builtin_amdgcn_mfma_f32_32x32x16_bf16(pf[f].v, vf.v, oacc[n], 0, 0, 0);
            }
        }

        // ---- convert prefetched regs -> LDS buf nxt; single barrier ----
        if (it < 31) {
            const float* pf32 = (const float*)pre;
            if (isK) {
                #pragma unroll
                for (int i = 0; i < 4; ++i) {
                    uint2 w;
                    w.x = pack_bf16(pre[i].x, pre[i].y);
                    w.y = pack_bf16(pre[i].z, pre[i].w);
                    *(uint2*)&KsLds[nxt][(srow + i * 16) * 68 + scol * 4] = w;
                }
            } else {
                #pragma unroll
                for (int c = 0; c < 4; ++c) {
                    uint2 w;
                    w.x = pack_bf16(pf32[0 * 4 + c], pf32[1 * 4 + c]);
                    w.y = pack_bf16(pf32[2 * 4 + c], pf32[3 * 4 + c]);
                    *(uint2*)&VtLds[nxt][(scol * 4 + c) * 68 + srow * 4] = w;
                }
            }
            __syncthreads();
        }
    }

    // ---- store (x ln2): C layout row=q_local, col=d_local ----
    float* obase = Og + (size_t)(b * SEQ) * DMODEL + head * HD;
    #pragma unroll
    for (int r = 0; r < 16; ++r) {
        int q = q0w + (r & 3) + 8 * (r >> 2) + 4 * half;
        float* orow = obase + (size_t)q * DMODEL;
        #pragma unroll
        for (int n = 0; n < 2; ++n)
            orow[n * 32 + l31] = oacc[n][r] * LN2;
    }
}

extern "C" void kernel_launch(void* const* d_in, const int* in_sizes, int n_in,
                              void* d_out, int out_size, void* d_ws, size_t ws_size,
                              hipStream_t stream) {
    const float* v  = (const float*)d_in[0];
    const float* k  = (const float*)d_in[1];
    const float* q  = (const float*)d_in[2];
    const float* rw = (const float*)d_in[3];
    float* out = (float*)d_out;
    paa_kernel<<<dim3(512), dim3(512), 0, stream>>>(v, k, q, rw, out);
}

// Round 6
// 231.693 us; speedup vs baseline: 2.0503x; 2.0503x over previous
//
#include <hip/hip_runtime.h>

#define SEQ 2048
#define NH 16
#define HD 64
#define DMODEL 1024

typedef short bf16x8 __attribute__((ext_vector_type(8)));
typedef float f32x16 __attribute__((ext_vector_type(16)));

union FragU {
    bf16x8 v;
    uint4 u4;
    uint2 u2[2];
    unsigned int w[4];
    unsigned short s[8];
};

#if __has_builtin(__builtin_amdgcn_cvt_pk_bf16_f32)
typedef __bf16 v2bf_t __attribute__((ext_vector_type(2)));
__device__ __forceinline__ unsigned int pack_bf16(float lo, float hi) {
    union { v2bf_t h; unsigned int u; } cv;
    cv.h = __builtin_amdgcn_cvt_pk_bf16_f32(lo, hi);
    return cv.u;
}
#else
__device__ __forceinline__ unsigned int pack_bf16(float lo, float hi) {
    unsigned int a = __float_as_uint(lo) + 0x8000u;
    unsigned int b = __float_as_uint(hi) + 0x8000u;
    return __builtin_amdgcn_perm(b, a, 0x07060302);
}
#endif

typedef __attribute__((address_space(1))) const unsigned int glob_u32;
typedef __attribute__((address_space(3))) unsigned int lds_u32;
// async global->LDS DMA, 16B/lane; LDS dest = uniform base + lane*16
__device__ __forceinline__ void dma16(const unsigned short* g, unsigned short* l) {
    __builtin_amdgcn_global_load_lds((glob_u32*)g, (lds_u32*)l, 16, 0, 0);
}

#define EXP_SCALE 1.44269504f   // 1/ln2, folded into Q and bias table
#define LN2       0.69314718f   // folded into epilogue store

// ---------------- prepass: fp32 K,V -> bf16 ws (K row-swizzled; V transposed
// tile-contiguous, row-swizzled). Swizzle: 16B group g of row r stored at
// position g ^ (r&7) -> conflict-free LDS fragment reads in the main kernel.
__global__ __launch_bounds__(256)
void prep_kernel(const float* __restrict__ Kg, const float* __restrict__ Vg,
                 unsigned short* __restrict__ wsK, unsigned short* __restrict__ wsVt)
{
    __shared__ unsigned short T[64 * 68];
    const int tid = threadIdx.x;
    const int blk = blockIdx.x;      // 64 bh * 32 tiles
    const int bh  = blk >> 5;
    const int it  = blk & 31;
    const int b = bh >> 4, h = bh & 15;
    const size_t inbase = (size_t)(b * SEQ + it * 64) * DMODEL + h * HD;

    // K: 64 rows x 8 groups, swizzled bf16
    #pragma unroll
    for (int i = 0; i < 2; ++i) {
        int item = tid + i * 256;
        int row = item >> 3, g = item & 7;
        const float* src = Kg + inbase + (size_t)row * DMODEL + g * 8;
        float4 x0 = *(const float4*)src;
        float4 x1 = *(const float4*)(src + 4);
        uint4 w;
        w.x = pack_bf16(x0.x, x0.y); w.y = pack_bf16(x0.z, x0.w);
        w.z = pack_bf16(x1.x, x1.y); w.w = pack_bf16(x1.z, x1.w);
        size_t dst = (size_t)(bh * 2048 + it * 64 + row) * 64 + ((g ^ (row & 7)) * 8);
        *(uint4*)&wsK[dst] = w;
    }
    // V -> LDS transposed bf16 (T[d][kc], stride 68)
    {
        const int kc4 = tid >> 4, d4 = tid & 15;
        float4 a[4];
        #pragma unroll
        for (int r = 0; r < 4; ++r)
            a[r] = *(const float4*)(Vg + inbase + (size_t)(kc4 * 4 + r) * DMODEL + d4 * 4);
        const float* af = (const float*)a;
        #pragma unroll
        for (int c = 0; c < 4; ++c) {
            *(unsigned int*)&T[(d4 * 4 + c) * 68 + kc4 * 4]     = pack_bf16(af[0 * 4 + c], af[1 * 4 + c]);
            *(unsigned int*)&T[(d4 * 4 + c) * 68 + kc4 * 4 + 2] = pack_bf16(af[2 * 4 + c], af[3 * 4 + c]);
        }
    }
    __syncthreads();
    // Vt tile out (64 d-rows x 64 kc), swizzled, 8KB contiguous per tile
    #pragma unroll
    for (int i = 0; i < 2; ++i) {
        int item = tid + i * 256;
        int d = item >> 3, g = item & 7;
        uint2 lo = *(const uint2*)&T[d * 68 + g * 8];
        uint2 hi = *(const uint2*)&T[d * 68 + g * 8 + 4];
        uint4 w; w.x = lo.x; w.y = lo.y; w.z = hi.x; w.w = hi.y;
        size_t dst = (size_t)(bh * 32 + it) * 4096 + d * 64 + ((g ^ (d & 7)) * 8);
        *(uint4*)&wsVt[dst] = w;
    }
}

// ---------------- main: 512 threads = 8 waves, wave = 32q x 64d.
// K/Vt tiles DMA'd from ws (bf16, pre-swizzled) into double-buffered LDS,
// one barrier per tile. X^T = 1.4427*(K*Q^T+bias) w/ bias-init accumulator;
// p = x*rcp(1+exp2(-x)); P feeds PV MFMA directly; epilogue * ln2.
__global__ __launch_bounds__(512, 4)
void paa_main(const unsigned short* __restrict__ wsK, const unsigned short* __restrict__ wsVt,
              const float* __restrict__ Qg, const float* __restrict__ RW,
              float* __restrict__ Og)
{
    __shared__ __align__(16) unsigned short KsT[2 * 4096];  // [buf][kc][d-groups swizzled]
    __shared__ __align__(16) unsigned short VtT[2 * 4096];  // [buf][d][kc-groups swizzled]
    __shared__ float btab[128];

    const int tid  = threadIdx.x;
    const int lane = tid & 63;
    const int wave = tid >> 6;   // 0..7
    const int half = lane >> 5;
    const int l31  = lane & 31;
    const int c7   = l31 & 7;

    const int bid  = blockIdx.x;
    const int bh   = bid & 63;
    const int qt   = bid >> 6;
    const int b    = bh >> 4;
    const int head = bh & 15;
    const int q0w  = qt * 256 + wave * 32;

    // bias table (pre-scaled by 1/ln2)
    if (tid < 128) {
        int rp = tid;
        int bucket;
        if (rp < 16) bucket = rp;
        else {
            int big = 16 + (int)(logf((float)rp * 0.0625f) * 7.6943736f);
            bucket = big < 31 ? big : 31;
        }
        btab[tid] = RW[bucket * NH + head] * EXP_SCALE;
    }

    // per-lane DMA source pointers (ushort units); tile stride 4096
    const unsigned short* kIt = wsK  + (size_t)bh * 131072 + wave * 512 + lane * 8;
    const unsigned short* vIt = wsVt + (size_t)bh * 131072 + wave * 512 + lane * 8;

    // prologue: DMA tile 0 into buf 0
    dma16(kIt, &KsT[wave * 512]);
    dma16(vIt, &VtT[wave * 512]);

    // preload Q fragments (B operand), pre-scaled by 1/ln2
    FragU qf[4];
    {
        const float* qrow = Qg + (size_t)(b * SEQ + q0w + l31) * DMODEL + head * HD;
        #pragma unroll
        for (int kf = 0; kf < 4; ++kf) {
            int dd = kf * 16 + half * 8;
            float4 x0 = *(const float4*)(qrow + dd);
            float4 x1 = *(const float4*)(qrow + dd + 4);
            FragU f;
            f.w[0] = pack_bf16(x0.x * EXP_SCALE, x0.y * EXP_SCALE);
            f.w[1] = pack_bf16(x0.z * EXP_SCALE, x0.w * EXP_SCALE);
            f.w[2] = pack_bf16(x1.x * EXP_SCALE, x1.y * EXP_SCALE);
            f.w[3] = pack_bf16(x1.z * EXP_SCALE, x1.w * EXP_SCALE);
            qf[kf] = f;
        }
    }

    f32x16 oacc[2];
    #pragma unroll
    for (int n = 0; n < 2; ++n)
        #pragma unroll
        for (int r = 0; r < 16; ++r) oacc[n][r] = 0.0f;

    __syncthreads();   // btab + tile-0 DMA complete (vmcnt(0) before barrier)
    const float bias_d0  = btab[0];
    const float bias_far = btab[127];

    // per-lane fragment address bases (ushort units within a tile)
    const int kaP = l31 * 64 + c7 * 8;             // ka: row l31, swizzle base
    const int vfP = l31 * 64 + c7 * 8 + half * 4;  // vf: row l31, +inner half*4

    auto compute_tile = [&](const int BUF, const int it) {
        const int kcb = it * 64;
        const unsigned short* kb = &KsT[BUF * 4096];
        const unsigned short* vb = &VtT[BUF * 4096];
        FragU pf[4];
        #pragma unroll
        for (int t = 0; t < 2; ++t) {
            const int kcmin = kcb + t * 32;
            FragU ka[4];
            #pragma unroll
            for (int kf = 0; kf < 4; ++kf) {
                int g8 = (2 * kf + half) * 8;
                ka[kf].u4 = *(const uint4*)&kb[t * 2048 + (kaP ^ g8)];
            }
            // scalar-branched bias case (wave-uniform by construction)
            int tcase = (q0w + 31 <= kcmin) ? 0 : ((q0w - (kcmin + 31) >= 113) ? 1 : 2);
            tcase = __builtin_amdgcn_readfirstlane(tcase);
            f32x16 st;
            if (tcase == 0) {
                #pragma unroll
                for (int r = 0; r < 16; ++r) st[r] = bias_d0;
            } else if (tcase == 1) {
                #pragma unroll
                for (int r = 0; r < 16; ++r) st[r] = bias_far;
            } else {
                const int dql = q0w + l31 - kcmin - 4 * half;
                #pragma unroll
                for (int r = 0; r < 16; ++r) {
                    int dv = dql - ((r & 3) + 8 * (r >> 2));
                    dv = dv < 0 ? 0 : (dv > 127 ? 127 : dv);
                    st[r] = btab[dv];
                }
            }
            #pragma unroll
            for (int kf = 0; kf < 4; ++kf)
                st = __builtin_amdgcn_mfma_f32_32x32x16_bf16(ka[kf].v, qf[kf].v, st, 0, 0, 0);

            // p = x * rcp(1 + exp2(-x))  == 1.4427 * silu(x*ln2)
            float vals[16];
            #pragma unroll
            for (int r = 0; r < 16; ++r) {
                float x = st[r];
                float e = __builtin_amdgcn_exp2f(-x);
                vals[r] = x * __builtin_amdgcn_rcpf(1.0f + e);
            }
            #pragma unroll
            for (int j = 0; j < 4; ++j)
                pf[t * 2].w[j]     = pack_bf16(vals[2 * j], vals[2 * j + 1]);
            #pragma unroll
            for (int j = 0; j < 4; ++j)
                pf[t * 2 + 1].w[j] = pack_bf16(vals[8 + 2 * j], vals[9 + 2 * j]);
        }

        // O += P * V (vf pieces address-matched to P's k-slot permutation)
        #pragma unroll
        for (int f = 0; f < 4; ++f) {
            #pragma unroll
            for (int n = 0; n < 2; ++n) {
                FragU vf;
                const int base = n * 2048;
                vf.u2[0] = *(const uint2*)&vb[base + (vfP ^ (2 * f * 8))];
                vf.u2[1] = *(const uint2*)&vb[base + (vfP ^ ((2 * f + 1) * 8))];
                oacc[n] = __builtin_amdgcn_mfma_f32_32x32x16_bf16(pf[f].v, vf.v, oacc[n], 0, 0, 0);
            }
        }
    };

    for (int it2 = 0; it2 < 16; ++it2) {
        const int it = it2 * 2;
        // even body: compute buf0(tile it); DMA tile it+1 -> buf1 (it+1<=31 always)
        kIt += 4096; vIt += 4096;
        dma16(kIt, &KsT[4096 + wave * 512]);
        dma16(vIt, &VtT[4096 + wave * 512]);
        compute_tile(0, it);
        __syncthreads();
        // odd body: compute buf1(tile it+1); DMA tile it+2 -> buf0
        if (it2 < 15) {
            kIt += 4096; vIt += 4096;
            dma16(kIt, &KsT[wave * 512]);
            dma16(vIt, &VtT[wave * 512]);
        }
        compute_tile(1, it + 1);
        __syncthreads();
    }

    // store (x ln2): C layout row=q_local, col=d_local
    float* obase = Og + (size_t)(b * SEQ) * DMODEL + head * HD;
    #pragma unroll
    for (int r = 0; r < 16; ++r) {
        int q = q0w + (r & 3) + 8 * (r >> 2) + 4 * half;
        float* orow = obase + (size_t)q * DMODEL;
        #pragma unroll
        for (int n = 0; n < 2; ++n)
            orow[n * 32 + l31] = oacc[n][r] * LN2;
    }
}

extern "C" void kernel_launch(void* const* d_in, const int* in_sizes, int n_in,
                              void* d_out, int out_size, void* d_ws, size_t ws_size,
                              hipStream_t stream) {
    const float* v  = (const float*)d_in[0];
    const float* k  = (const float*)d_in[1];
    const float* q  = (const float*)d_in[2];
    const float* rw = (const float*)d_in[3];
    float* out = (float*)d_out;
    unsigned short* wsK  = (unsigned short*)d_ws;
    unsigned short* wsVt = wsK + (size_t)4 * NH * SEQ * HD;   // +16.78MB (need 33.6MB total)
    prep_kernel<<<dim3(2048), dim3(256), 0, stream>>>(k, v, wsK, wsVt);
    paa_main<<<dim3(512), dim3(512), 0, stream>>>(wsK, wsVt, q, rw, out);
}